// Round 1
// baseline (433.464 us; speedup 1.0000x reference)
//
#include <hip/hip_runtime.h>

// out = clip(x + laplace_noise * mask, 0, 1), element-wise over
// N = 256*3*224*224 = 38,535,168 fp32 elements. Memory-bound.
// Inputs (setup_inputs order): x[N] f32, eps[1] (unused — baked into mask),
// laplace_noise[N] f32, mask[N] f32. Output: f32[N].

__global__ __launch_bounds__(256) void rrn_clip_kernel(
    const float4* __restrict__ x,
    const float4* __restrict__ lap,
    const float4* __restrict__ mask,
    float4* __restrict__ out,
    int n4)
{
    int i = blockIdx.x * blockDim.x + threadIdx.x;
    if (i >= n4) return;

    float4 xv = x[i];
    float4 lv = lap[i];
    float4 mv = mask[i];

    float4 o;
    o.x = fminf(fmaxf(fmaf(lv.x, mv.x, xv.x), 0.0f), 1.0f);
    o.y = fminf(fmaxf(fmaf(lv.y, mv.y, xv.y), 0.0f), 1.0f);
    o.z = fminf(fmaxf(fmaf(lv.z, mv.z, xv.z), 0.0f), 1.0f);
    o.w = fminf(fmaxf(fmaf(lv.w, mv.w, xv.w), 0.0f), 1.0f);

    out[i] = o;
}

extern "C" void kernel_launch(void* const* d_in, const int* in_sizes, int n_in,
                              void* d_out, int out_size, void* d_ws, size_t ws_size,
                              hipStream_t stream)
{
    const float4* x    = (const float4*)d_in[0];
    // d_in[1] = eps (scalar) — unused; Bernoulli keep-prob already in mask.
    const float4* lap  = (const float4*)d_in[2];
    const float4* mask = (const float4*)d_in[3];
    float4* out        = (float4*)d_out;

    int n  = out_size;           // 38,535,168 — divisible by 4
    int n4 = n >> 2;             // 9,633,792 float4 elements

    const int block = 256;
    const int grid  = (n4 + block - 1) / block;   // 37,632 blocks

    rrn_clip_kernel<<<grid, block, 0, stream>>>(x, lap, mask, out, n4);
}